// Round 5
// baseline (1094.509 us; speedup 1.0000x reference)
//
#include <hip/hip_runtime.h>
#include <hip/hip_cooperative_groups.h>

namespace cg = cooperative_groups;

#define DD 128
#define D2 64        // DD/2 packed-uint columns
#define BW_DST 32
#define BW_SHIFT 5
#define NBPAD 320    // >= ceil(N/32) = 313
#define P2CAP 2880
#define BT 256
#define BATCH_C 2048 // coop bucket_fill batch
#define BATCH_F 4096 // fallback bucket_fill batch
#define MAXGRID 1024

struct alignas(8) Rec { unsigned int meta; float w; };  // meta = src | (dstloc<<27)

__device__ __forceinline__ unsigned int bf16rne(float f) {
    unsigned int u = __float_as_uint(f);
    unsigned int r = ((u >> 16) & 1u) + 0x7fffu;
    return (u + r) >> 16;
}

// ------------------------- cooperative fused kernel -------------------------

union SMem {
    struct {
        unsigned short sbkt[BATCH_C];
        int cnt[NBPAD];
        int boff[NBPAD + 1];
        int gbase[NBPAD];
        int lcur[NBPAD];
        Rec staged[BATCH_C];
        int wpart[BT];
    } p1;                                               // ~26.6 KB
    struct { Rec staged[P2CAP]; int dcur[BW_DST]; } p2; // ~23.2 KB
    struct { float xs[16][DD]; } g;                     // 8 KB
    struct { int scan[512]; } s;
};

__global__ __launch_bounds__(BT, 4) void fused_gcn(
    const float* __restrict__ z, const int* __restrict__ src, const int* __restrict__ dst,
    const float* __restrict__ Ws, const float* __restrict__ bs,
    const float* __restrict__ gammas, const float* __restrict__ betas,
    float* __restrict__ dout,
    int* __restrict__ degi, float* __restrict__ dinv, int* __restrict__ row_ptr,
    int* __restrict__ bsum, int* __restrict__ bbase, int* __restrict__ bcur,
    Rec* __restrict__ bcsr, Rec* __restrict__ csr,
    unsigned int* __restrict__ xwb, float* __restrict__ xb,
    int N, int E, int L, int NB)
{
    cg::grid_group grid = cg::this_grid();
    __shared__ SMem sm;
    const int t = threadIdx.x;
    const int gtid = blockIdx.x * BT + t;
    const int gsz = gridDim.x * BT;

    // P0: zero edge-indegree histogram
    for (int i = gtid; i < N; i += gsz) degi[i] = 0;
    grid.sync();

    // P1: histogram of dst
    for (int e = gtid; e < E; e += gsz) atomicAdd(&degi[dst[e]], 1);
    grid.sync();

    // P2: dinv (deg + self-loop) + bucket-local exclusive prefix + bucket sums
    for (int i = gtid; i < N; i += gsz) dinv[i] = rsqrtf((float)(degi[i] + 1));
    {
        int wid = t >> 6, lane = t & 63;
        int gw = blockIdx.x * 4 + wid, nw = gridDim.x * 4;
        for (int b = gw; b < NB; b += nw) {
            if (lane < 32) {
                int d0 = b << BW_SHIFT, idx = d0 + lane;
                int c = (idx < N) ? degi[idx] : 0;
                int v = c;
                #pragma unroll
                for (int o = 1; o < 32; o <<= 1) { int u = __shfl_up(v, o, 32); if (lane >= o) v += u; }
                if (idx < N) row_ptr[idx] = v - c;
                if (lane == 31) bsum[b] = v;
            }
        }
    }
    grid.sync();

    // P3: block 0 scans bucket sums -> exclusive bucket bases (NB <= 512)
    if (blockIdx.x == 0) {
        sm.s.scan[t]       = (t < NB) ? bsum[t] : 0;
        sm.s.scan[256 + t] = (256 + t < NB) ? bsum[256 + t] : 0;
        __syncthreads();
        for (int o = 1; o < 512; o <<= 1) {
            int a0 = (t >= o) ? sm.s.scan[t - o] : 0;
            int a1 = (256 + t >= o) ? sm.s.scan[256 + t - o] : 0;
            __syncthreads();
            sm.s.scan[t] += a0;
            sm.s.scan[256 + t] += a1;
            __syncthreads();
        }
        if (t < NB) bbase[t] = (t == 0) ? 0 : sm.s.scan[t - 1];
        if (256 + t < NB) bbase[256 + t] = sm.s.scan[255 + t];
    }
    grid.sync();

    // P4: globalize row_ptr, init bucket cursors
    for (int i = gtid; i < N; i += gsz) row_ptr[i] += bbase[i >> BW_SHIFT];
    for (int b = gtid; b < NB; b += gsz) bcur[b] = bbase[b];
    if (gtid == 0) row_ptr[N] = E;
    grid.sync();

    // P5: bucket_fill — LDS counting-sort per batch, contiguous flush
    for (int base0 = blockIdx.x * BATCH_C; base0 < E; base0 += gridDim.x * BATCH_C) {
        int n = min(E - base0, BATCH_C);
        for (int b = t; b < NB; b += BT) sm.p1.cnt[b] = 0;
        __syncthreads();
        for (int i = t; i < n; i += BT) {
            int d = dst[base0 + i];
            int bk = d >> BW_SHIFT;
            sm.p1.sbkt[i] = (unsigned short)bk;
            atomicAdd(&sm.p1.cnt[bk], 1);
        }
        __syncthreads();
        int chunk = (NB + BT - 1) / BT;
        int lo = t * chunk, hi = min(lo + chunk, NB);
        int s = 0;
        for (int b = lo; b < hi; ++b) s += sm.p1.cnt[b];
        sm.p1.wpart[t] = s;
        __syncthreads();
        for (int o = 1; o < BT; o <<= 1) {
            int v = (t >= o) ? sm.p1.wpart[t - o] : 0;
            __syncthreads();
            sm.p1.wpart[t] += v;
            __syncthreads();
        }
        int run = (t == 0) ? 0 : sm.p1.wpart[t - 1];
        for (int b = lo; b < hi; ++b) {
            sm.p1.boff[b] = run;
            sm.p1.lcur[b] = run;
            if (sm.p1.cnt[b] > 0) sm.p1.gbase[b] = atomicAdd(&bcur[b], sm.p1.cnt[b]);
            run += sm.p1.cnt[b];
        }
        if (t == 0) sm.p1.boff[NB] = n;
        __syncthreads();
        for (int i = t; i < n; i += BT) {
            int e = base0 + i;
            int ss = src[e], dd2 = dst[e];
            int bk = sm.p1.sbkt[i];
            int p = atomicAdd(&sm.p1.lcur[bk], 1);
            Rec r;
            r.meta = (unsigned int)ss | ((unsigned int)(dd2 & (BW_DST - 1)) << 27);
            r.w = dinv[ss] * dinv[dd2];
            sm.p1.staged[p] = r;
        }
        __syncthreads();
        int wid = t >> 6, lane = t & 63;
        for (int b = wid; b < NB; b += 4) {
            int s0 = sm.p1.boff[b];
            int c = sm.p1.boff[b + 1] - s0;
            if (c == 0) continue;
            int g0 = sm.p1.gbase[b];
            for (int j = lane; j < c; j += 64) bcsr[g0 + j] = sm.p1.staged[s0 + j];
        }
        __syncthreads();
    }
    grid.sync();

    // P6: fine_sort per bucket
    for (int b = blockIdx.x; b < NB; b += gridDim.x) {
        int d0 = b << BW_SHIFT;
        int nd = min(BW_DST, N - d0);
        int base = row_ptr[d0];
        int end = row_ptr[min(d0 + nd, N)];
        int cnt2 = end - base;
        if (t < nd) sm.p2.dcur[t] = row_ptr[d0 + t] - base;
        __syncthreads();
        if (cnt2 <= P2CAP) {
            for (int i = t; i < cnt2; i += BT) {
                Rec r = bcsr[base + i];
                int dl = r.meta >> 27;
                int p = atomicAdd(&sm.p2.dcur[dl], 1);
                sm.p2.staged[p] = r;
            }
            __syncthreads();
            for (int i = t; i < cnt2; i += BT) csr[base + i] = sm.p2.staged[i];
        } else {
            for (int i = t; i < cnt2; i += BT) {
                Rec r = bcsr[base + i];
                int dl = r.meta >> 27;
                int p = atomicAdd(&sm.p2.dcur[dl], 1);
                csr[base + p] = r;
            }
        }
        __syncthreads();
    }
    grid.sync();

    // Layers
    int ngroups = (N + 15) >> 4;
    for (int li = 0; li < L; ++li) {
        const float* x = (li == 0) ? z : xb;
        const float* W = Ws + (size_t)li * DD * DD;
        for (int g = blockIdx.x; g < ngroups; g += gridDim.x) {
            int r0 = g << 4;
            for (int j = t; j < 16 * DD; j += BT) {
                int r = j >> 7, c2 = j & 127;
                int row = r0 + r;
                sm.g.xs[r][c2] = (row < N) ? x[row * DD + c2] : 0.f;
            }
            __syncthreads();
            int col = t & 127;
            int h = t >> 7;
            float acc[8];
            #pragma unroll
            for (int r = 0; r < 8; ++r) acc[r] = 0.f;
            for (int k = 0; k < DD; k += 4) {
                float w0 = W[(k + 0) * DD + col];
                float w1 = W[(k + 1) * DD + col];
                float w2 = W[(k + 2) * DD + col];
                float w3 = W[(k + 3) * DD + col];
                #pragma unroll
                for (int r = 0; r < 8; ++r) {
                    float4 xv = *(const float4*)&sm.g.xs[h * 8 + r][k];
                    acc[r] = fmaf(xv.x, w0, acc[r]);
                    acc[r] = fmaf(xv.y, w1, acc[r]);
                    acc[r] = fmaf(xv.z, w2, acc[r]);
                    acc[r] = fmaf(xv.w, w3, acc[r]);
                }
            }
            #pragma unroll
            for (int r = 0; r < 8; ++r) {
                int row = r0 + h * 8 + r;
                float other = __shfl_xor(acc[r], 1);
                if (row < N && !(t & 1)) {
                    unsigned int p = bf16rne(acc[r]) | (bf16rne(other) << 16);
                    xwb[row * D2 + (col >> 1)] = p;
                }
            }
            __syncthreads();
        }
        grid.sync();

        float* outp = (li == L - 1) ? dout : xb;
        const float* bias = bs + (size_t)li * DD;
        const float* gam  = gammas + (size_t)li * DD;
        const float* bet  = betas + (size_t)li * DD;
        int wv = (blockIdx.x << 2) + (t >> 6);
        int l = t & 63;
        int nw = gridDim.x << 2;
        for (int i = wv; i < N; i += nw) {
            int beg = row_ptr[i], end2 = row_ptr[i + 1];
            float ax = 0.f, ay = 0.f;
            for (int j = beg; j < end2; ++j) {
                Rec er = csr[j];
                unsigned int v = xwb[(er.meta & 0x07FFFFFF) * D2 + l];
                ax = fmaf(__uint_as_float(v << 16), er.w, ax);
                ay = fmaf(__uint_as_float(v & 0xFFFF0000u), er.w, ay);
            }
            float di = dinv[i];
            float sn = di * di;
            unsigned int v = xwb[i * D2 + l];
            ax = fmaf(__uint_as_float(v << 16), sn, ax);
            ay = fmaf(__uint_as_float(v & 0xFFFF0000u), sn, ay);
            float2 b2 = ((const float2*)bias)[l];
            ax += b2.x; ay += b2.y;
            float sum = ax + ay, sq = ax * ax + ay * ay;
            #pragma unroll
            for (int o = 32; o > 0; o >>= 1) { sum += __shfl_xor(sum, o); sq += __shfl_xor(sq, o); }
            float mu   = sum * (1.f / DD);
            float var  = sq * (1.f / DD) - mu * mu;
            float rstd = rsqrtf(var + 1e-5f);
            float2 g2  = ((const float2*)gam)[l];
            float2 be2 = ((const float2*)bet)[l];
            float y0 = (ax - mu) * rstd * g2.x + be2.x;
            float y1 = (ay - mu) * rstd * g2.y + be2.y;
            y0 = 0.5f * y0 * (1.f + tanhf(0.7978845608f * (y0 + 0.044715f * y0 * y0 * y0)));
            y1 = 0.5f * y1 * (1.f + tanhf(0.7978845608f * (y1 + 0.044715f * y1 * y1 * y1)));
            float2 o2; o2.x = y0; o2.y = y1;
            ((float2*)outp)[i * D2 + l] = o2;
        }
        if (li != L - 1) grid.sync();
    }
}

// ------------------------- fallback pipeline (round-3, proven) -------------------------

__global__ void init_deg(int* __restrict__ degi, int N) {
    int i = blockIdx.x * blockDim.x + threadIdx.x;
    if (i < N) degi[i] = 1;
}

__global__ void hist_dst(const int* __restrict__ dst, int E, int* __restrict__ degi) {
    int e = blockIdx.x * blockDim.x + threadIdx.x;
    if (e < E) atomicAdd(&degi[dst[e]], 1);
}

__global__ void compute_dinv(const int* __restrict__ degi, float* __restrict__ dinv, int N) {
    int i = blockIdx.x * blockDim.x + threadIdx.x;
    if (i < N) dinv[i] = rsqrtf((float)degi[i]);
}

__global__ void scan_rowptr(const int* __restrict__ degi, int* __restrict__ row_ptr,
                            int N, int E) {
    __shared__ int part[256];
    int t = threadIdx.x;
    int chunk = (N + 255) / 256;
    int lo = t * chunk, hi = min(lo + chunk, N);
    int s = 0;
    for (int i = lo; i < hi; ++i) s += degi[i] - 1;
    part[t] = s;
    __syncthreads();
    for (int o = 1; o < 256; o <<= 1) {
        int v = (t >= o) ? part[t - o] : 0;
        __syncthreads();
        part[t] += v;
        __syncthreads();
    }
    int run = (t == 0) ? 0 : part[t - 1];
    for (int i = lo; i < hi; ++i) { row_ptr[i] = run; run += degi[i] - 1; }
    if (t == 0) row_ptr[N] = E;
}

__global__ void init_bcur(const int* __restrict__ row_ptr, int* __restrict__ bcur,
                          int NB, int N) {
    int b = blockIdx.x * blockDim.x + threadIdx.x;
    if (b < NB) bcur[b] = row_ptr[min(b * BW_DST, N)];
}

__global__ __launch_bounds__(256) void bucket_fill_f(
    const int* __restrict__ src, const int* __restrict__ dst, int E,
    const float* __restrict__ dinv, int* __restrict__ bcur,
    Rec* __restrict__ bcsr, int NB)
{
    __shared__ unsigned short sbkt[BATCH_F];
    __shared__ int cnt[NBPAD];
    __shared__ int boff[NBPAD + 1];
    __shared__ int gbase[NBPAD];
    __shared__ int lcur[NBPAD];
    __shared__ Rec staged[BATCH_F];
    __shared__ int wpart[256];
    int t = threadIdx.x;

    for (int base = blockIdx.x * BATCH_F; base < E; base += gridDim.x * BATCH_F) {
        int n = min(E - base, BATCH_F);
        for (int b = t; b < NB; b += 256) cnt[b] = 0;
        __syncthreads();
        for (int i = t; i < n; i += 256) {
            int d = dst[base + i];
            int bk = d >> BW_SHIFT;
            sbkt[i] = (unsigned short)bk;
            atomicAdd(&cnt[bk], 1);
        }
        __syncthreads();
        int chunk = (NB + 255) / 256;
        int lo = t * chunk, hi = min(lo + chunk, NB);
        int s = 0;
        for (int b = lo; b < hi; ++b) s += cnt[b];
        wpart[t] = s;
        __syncthreads();
        for (int o = 1; o < 256; o <<= 1) {
            int v = (t >= o) ? wpart[t - o] : 0;
            __syncthreads();
            wpart[t] += v;
            __syncthreads();
        }
        int run = (t == 0) ? 0 : wpart[t - 1];
        for (int b = lo; b < hi; ++b) {
            boff[b] = run;
            lcur[b] = run;
            if (cnt[b] > 0) gbase[b] = atomicAdd(&bcur[b], cnt[b]);
            run += cnt[b];
        }
        if (t == 0) boff[NB] = n;
        __syncthreads();
        for (int i = t; i < n; i += 256) {
            int e = base + i;
            int ss = src[e], dd = dst[e];
            int bk = sbkt[i];
            int p = atomicAdd(&lcur[bk], 1);
            Rec r;
            r.meta = (unsigned int)ss | ((unsigned int)(dd & (BW_DST - 1)) << 27);
            r.w = dinv[ss] * dinv[dd];
            staged[p] = r;
        }
        __syncthreads();
        int wid = t >> 6, lane = t & 63;
        for (int b = wid; b < NB; b += 4) {
            int s0 = boff[b];
            int c = boff[b + 1] - s0;
            if (c == 0) continue;
            int g = gbase[b];
            for (int j = lane; j < c; j += 64) bcsr[g + j] = staged[s0 + j];
        }
        __syncthreads();
    }
}

__global__ __launch_bounds__(256) void fine_sort_f(
    const int* __restrict__ row_ptr, const Rec* __restrict__ bcsr,
    Rec* __restrict__ csr, int N)
{
    __shared__ Rec staged[P2CAP];
    __shared__ int dcur[BW_DST];
    int b = blockIdx.x;
    int d0 = b * BW_DST;
    int nd = min(BW_DST, N - d0);
    int base = row_ptr[d0];
    int end  = row_ptr[min(d0 + nd, N)];
    int cnt  = end - base;
    int t = threadIdx.x;
    if (t < nd) dcur[t] = row_ptr[d0 + t] - base;
    __syncthreads();
    if (cnt <= P2CAP) {
        for (int i = t; i < cnt; i += 256) {
            Rec r = bcsr[base + i];
            int dl = r.meta >> 27;
            int p = atomicAdd(&dcur[dl], 1);
            staged[p] = r;
        }
        __syncthreads();
        for (int i = t; i < cnt; i += 256) csr[base + i] = staged[i];
    } else {
        for (int i = t; i < cnt; i += 256) {
            Rec r = bcsr[base + i];
            int dl = r.meta >> 27;
            int p = atomicAdd(&dcur[dl], 1);
            csr[base + p] = r;
        }
    }
}

#define GR 16
__global__ void gemm_xw(const float* __restrict__ x, const float* __restrict__ W,
                        unsigned int* __restrict__ xwb, int N) {
    __shared__ float xs[GR][DD];
    int t = threadIdx.x;
    int r0 = blockIdx.x * GR;
    #pragma unroll
    for (int r = 0; r < GR; ++r) {
        int row = r0 + r;
        xs[r][t] = (row < N) ? x[row * DD + t] : 0.f;
    }
    __syncthreads();
    float acc[GR];
    #pragma unroll
    for (int r = 0; r < GR; ++r) acc[r] = 0.f;
    for (int k = 0; k < DD; k += 4) {
        float w0 = W[(k + 0) * DD + t];
        float w1 = W[(k + 1) * DD + t];
        float w2 = W[(k + 2) * DD + t];
        float w3 = W[(k + 3) * DD + t];
        #pragma unroll
        for (int r = 0; r < GR; ++r) {
            float4 xv = *(const float4*)&xs[r][k];
            acc[r] = fmaf(xv.x, w0, acc[r]);
            acc[r] = fmaf(xv.y, w1, acc[r]);
            acc[r] = fmaf(xv.z, w2, acc[r]);
            acc[r] = fmaf(xv.w, w3, acc[r]);
        }
    }
    #pragma unroll
    for (int r = 0; r < GR; ++r) {
        int row = r0 + r;
        float other = __shfl_xor(acc[r], 1);
        if (row < N && !(t & 1)) {
            unsigned int p = bf16rne(acc[r]) | (bf16rne(other) << 16);
            xwb[row * D2 + (t >> 1)] = p;
        }
    }
}

__global__ void agg_ln_gelu(const unsigned int* __restrict__ xwb, const Rec* __restrict__ csr,
                            const int* __restrict__ row_ptr, const float* __restrict__ dinv,
                            const float* __restrict__ bias, const float* __restrict__ gamma,
                            const float* __restrict__ beta, float* __restrict__ out) {
    int i = blockIdx.x;
    int l = threadIdx.x;
    int beg = row_ptr[i], end = row_ptr[i + 1];
    float ax = 0.f, ay = 0.f;
    for (int j = beg; j < end; ++j) {
        Rec er = csr[j];
        unsigned int v = xwb[(er.meta & 0x07FFFFFF) * D2 + l];
        ax = fmaf(__uint_as_float(v << 16), er.w, ax);
        ay = fmaf(__uint_as_float(v & 0xFFFF0000u), er.w, ay);
    }
    float di = dinv[i];
    float sn = di * di;
    unsigned int v = xwb[i * D2 + l];
    ax = fmaf(__uint_as_float(v << 16), sn, ax);
    ay = fmaf(__uint_as_float(v & 0xFFFF0000u), sn, ay);
    float2 b2 = ((const float2*)bias)[l];
    ax += b2.x; ay += b2.y;
    float sum = ax + ay, sq = ax * ax + ay * ay;
    #pragma unroll
    for (int o = 32; o > 0; o >>= 1) { sum += __shfl_xor(sum, o); sq += __shfl_xor(sq, o); }
    float mu   = sum * (1.f / DD);
    float var  = sq * (1.f / DD) - mu * mu;
    float rstd = rsqrtf(var + 1e-5f);
    float2 g2  = ((const float2*)gamma)[l];
    float2 be2 = ((const float2*)beta)[l];
    float y0 = (ax - mu) * rstd * g2.x + be2.x;
    float y1 = (ay - mu) * rstd * g2.y + be2.y;
    y0 = 0.5f * y0 * (1.f + tanhf(0.7978845608f * (y0 + 0.044715f * y0 * y0 * y0)));
    y1 = 0.5f * y1 * (1.f + tanhf(0.7978845608f * (y1 + 0.044715f * y1 * y1 * y1)));
    float2 o2; o2.x = y0; o2.y = y1;
    ((float2*)out)[i * D2 + l] = o2;
}

static inline size_t align_up(size_t x, size_t a) { return (x + a - 1) & ~(a - 1); }

extern "C" void kernel_launch(void* const* d_in, const int* in_sizes, int n_in,
                              void* d_out, int out_size, void* d_ws, size_t ws_size,
                              hipStream_t stream) {
    const float* z      = (const float*)d_in[0];
    const int*   ei     = (const int*)d_in[1];
    const float* Ws     = (const float*)d_in[2];
    const float* bs     = (const float*)d_in[3];
    const float* gammas = (const float*)d_in[4];
    const float* betas  = (const float*)d_in[5];

    int E  = in_sizes[1] / 2;
    int LD = in_sizes[3];
    int Dd = in_sizes[2] / LD;            // 128
    int L  = LD / Dd;
    int N  = in_sizes[0] / Dd;
    int NB = (N + BW_DST - 1) / BW_DST;   // 313

    const int* srcp = ei;
    const int* dstp = ei + E;

    char* ws = (char*)d_ws;
    size_t off = 0;
    int* degi = (int*)(ws + off);        off = align_up(off + (size_t)N * 4, 256);
    float* dinv = (float*)(ws + off);    off = align_up(off + (size_t)N * 4, 256);
    int* row_ptr = (int*)(ws + off);     off = align_up(off + (size_t)(N + 1) * 4, 256);
    int* bsum = (int*)(ws + off);        off = align_up(off + (size_t)NBPAD * 4, 256);
    int* bbase = (int*)(ws + off);       off = align_up(off + (size_t)NBPAD * 4, 256);
    int* bcur = (int*)(ws + off);        off = align_up(off + (size_t)NBPAD * 4, 256);
    Rec* bcsr = (Rec*)(ws + off);        off = align_up(off + (size_t)E * 8, 256);
    Rec* csr = (Rec*)(ws + off);         off = align_up(off + (size_t)E * 8, 256);
    unsigned int* xwb = (unsigned int*)(ws + off); off = align_up(off + (size_t)N * D2 * 4, 256);
    float* xb = (float*)(ws + off);      off = align_up(off + (size_t)N * Dd * 4, 256);
    float* dout = (float*)d_out;
    (void)ws_size; (void)n_in; (void)out_size;

    // size cooperative grid from the runtime's occupancy answer (host-side, capture-safe)
    int maxB = 0, nCU = 0, dev = 0;
    hipGetDevice(&dev);
    hipDeviceGetAttribute(&nCU, hipDeviceAttributeMultiprocessorCount, dev);
    hipError_t occ_rc = hipOccupancyMaxActiveBlocksPerMultiprocessor(
        &maxB, (const void*)fused_gcn, BT, 0);

    hipError_t rc = hipErrorUnknown;
    if (occ_rc == hipSuccess && maxB > 0 && nCU > 0) {
        int grid = maxB * nCU;
        if (grid > MAXGRID) grid = MAXGRID;
        void* args[] = { (void*)&z, (void*)&srcp, (void*)&dstp, (void*)&Ws, (void*)&bs,
                         (void*)&gammas, (void*)&betas, (void*)&dout,
                         (void*)&degi, (void*)&dinv, (void*)&row_ptr, (void*)&bsum,
                         (void*)&bbase, (void*)&bcur, (void*)&bcsr, (void*)&csr,
                         (void*)&xwb, (void*)&xb, (void*)&N, (void*)&E, (void*)&L, (void*)&NB };
        rc = hipLaunchCooperativeKernel((void*)fused_gcn, dim3(grid), dim3(BT),
                                        args, 0, stream);
    }
    if (rc == hipSuccess) return;

    // ---------- fallback: proven multi-kernel pipeline ----------
    int nb_n = (N + 255) / 256;
    int nb_e = (E + 255) / 256;
    int nb_p1 = (E + BATCH_F - 1) / BATCH_F;

    init_deg<<<nb_n, 256, 0, stream>>>(degi, N);
    hist_dst<<<nb_e, 256, 0, stream>>>(dstp, E, degi);
    compute_dinv<<<nb_n, 256, 0, stream>>>(degi, dinv, N);
    scan_rowptr<<<1, 256, 0, stream>>>(degi, row_ptr, N, E);
    init_bcur<<<(NB + 255) / 256, 256, 0, stream>>>(row_ptr, bcur, NB, N);
    bucket_fill_f<<<nb_p1, 256, 0, stream>>>(srcp, dstp, E, dinv, bcur, bcsr, NB);
    fine_sort_f<<<NB, 256, 0, stream>>>(row_ptr, bcsr, csr, N);

    const float* cur = z;
    for (int li = 0; li < L; ++li) {
        gemm_xw<<<(N + GR - 1) / GR, DD, 0, stream>>>(cur, Ws + (size_t)li * Dd * Dd, xwb, N);
        float* outp = (li == L - 1) ? dout : xb;
        agg_ln_gelu<<<N, 64, 0, stream>>>(xwb, csr, row_ptr, dinv,
                                          bs + (size_t)li * Dd, gammas + (size_t)li * Dd,
                                          betas + (size_t)li * Dd, outp);
        cur = outp;
    }
}

// Round 6
// 259.926 us; speedup vs baseline: 4.2109x; 4.2109x over previous
//
#include <hip/hip_runtime.h>

#define DD 128
#define D2 64        // DD/2 packed-uint columns
#define BW_DST 32
#define BW_SHIFT 5
#define BATCH 4096
#define NBPAD 320    // >= ceil(N/32) = 313
#define P2CAP 2880

struct alignas(8) Rec { unsigned int meta; float w; };  // meta = src | (dstloc<<27)

__device__ __forceinline__ unsigned int bf16rne(float f) {
    unsigned int u = __float_as_uint(f);
    unsigned int r = ((u >> 16) & 1u) + 0x7fffu;   // round-to-nearest-even
    return (u + r) >> 16;
}

__global__ void init_deg(int* __restrict__ degi, int N) {
    int i = blockIdx.x * blockDim.x + threadIdx.x;
    if (i < N) degi[i] = 1;   // self-loop
}

__global__ void hist_dst(const int* __restrict__ dst, int E, int* __restrict__ degi) {
    int e = blockIdx.x * blockDim.x + threadIdx.x;
    if (e < E) atomicAdd(&degi[dst[e]], 1);
}

// Single block: dinv + exclusive scan of edge counts -> row_ptr + bucket cursors.
__global__ void scan_all(const int* __restrict__ degi, float* __restrict__ dinv,
                         int* __restrict__ row_ptr, int* __restrict__ bcur,
                         int N, int E) {
    __shared__ int part[256];
    int t = threadIdx.x;
    for (int i = t; i < N; i += 256) dinv[i] = rsqrtf((float)degi[i]);
    int chunk = (N + 255) / 256;
    int lo = t * chunk, hi = min(lo + chunk, N);
    int s = 0;
    for (int i = lo; i < hi; ++i) s += degi[i] - 1;
    part[t] = s;
    __syncthreads();
    for (int o = 1; o < 256; o <<= 1) {
        int v = (t >= o) ? part[t - o] : 0;
        __syncthreads();
        part[t] += v;
        __syncthreads();
    }
    int run = (t == 0) ? 0 : part[t - 1];
    for (int i = lo; i < hi; ++i) {
        row_ptr[i] = run;
        if ((i & (BW_DST - 1)) == 0) bcur[i >> BW_SHIFT] = run;
        run += degi[i] - 1;
    }
    if (t == 0) row_ptr[N] = E;
}

// Pass 1: LDS counting-sort per 4096-edge batch, contiguous per-bucket flush.
__global__ __launch_bounds__(256) void bucket_fill(
    const int* __restrict__ src, const int* __restrict__ dst, int E,
    const float* __restrict__ dinv, int* __restrict__ bcur,
    Rec* __restrict__ bcsr, int NB)
{
    __shared__ unsigned short sbkt[BATCH];
    __shared__ int cnt[NBPAD];
    __shared__ int boff[NBPAD + 1];
    __shared__ int gbase[NBPAD];
    __shared__ int lcur[NBPAD];
    __shared__ Rec staged[BATCH];
    __shared__ int wpart[256];
    int t = threadIdx.x;

    for (int base = blockIdx.x * BATCH; base < E; base += gridDim.x * BATCH) {
        int n = min(E - base, BATCH);
        for (int b = t; b < NB; b += 256) cnt[b] = 0;
        __syncthreads();
        for (int i = t; i < n; i += 256) {
            int d = dst[base + i];
            int bk = d >> BW_SHIFT;
            sbkt[i] = (unsigned short)bk;
            atomicAdd(&cnt[bk], 1);
        }
        __syncthreads();
        int chunk = (NB + 255) / 256;
        int lo = t * chunk, hi = min(lo + chunk, NB);
        int s = 0;
        for (int b = lo; b < hi; ++b) s += cnt[b];
        wpart[t] = s;
        __syncthreads();
        for (int o = 1; o < 256; o <<= 1) {
            int v = (t >= o) ? wpart[t - o] : 0;
            __syncthreads();
            wpart[t] += v;
            __syncthreads();
        }
        int run = (t == 0) ? 0 : wpart[t - 1];
        for (int b = lo; b < hi; ++b) {
            boff[b] = run;
            lcur[b] = run;
            if (cnt[b] > 0) gbase[b] = atomicAdd(&bcur[b], cnt[b]);
            run += cnt[b];
        }
        if (t == 0) boff[NB] = n;
        __syncthreads();
        for (int i = t; i < n; i += 256) {
            int e = base + i;
            int ss = src[e], dd = dst[e];
            int bk = sbkt[i];
            int p = atomicAdd(&lcur[bk], 1);
            Rec r;
            r.meta = (unsigned int)ss | ((unsigned int)(dd & (BW_DST - 1)) << 27);
            r.w = dinv[ss] * dinv[dd];
            staged[p] = r;
        }
        __syncthreads();
        int wid = t >> 6, lane = t & 63;
        for (int b = wid; b < NB; b += 4) {
            int s0 = boff[b];
            int c = boff[b + 1] - s0;
            if (c == 0) continue;
            int g = gbase[b];
            for (int j = lane; j < c; j += 64) bcsr[g + j] = staged[s0 + j];
        }
        __syncthreads();
    }
}

// Pass 2: per bucket, fine-sort by dst via LDS, write coalesced.
__global__ __launch_bounds__(256) void fine_sort(
    const int* __restrict__ row_ptr, const Rec* __restrict__ bcsr,
    Rec* __restrict__ csr, int N)
{
    __shared__ Rec staged[P2CAP];
    __shared__ int dcur[BW_DST];
    int b = blockIdx.x;
    int d0 = b * BW_DST;
    int nd = min(BW_DST, N - d0);
    int base = row_ptr[d0];
    int end  = row_ptr[min(d0 + nd, N)];
    int cnt  = end - base;
    int t = threadIdx.x;
    if (t < nd) dcur[t] = row_ptr[d0 + t] - base;
    __syncthreads();
    if (cnt <= P2CAP) {
        for (int i = t; i < cnt; i += 256) {
            Rec r = bcsr[base + i];
            int dl = r.meta >> 27;
            int p = atomicAdd(&dcur[dl], 1);
            staged[p] = r;
        }
        __syncthreads();
        for (int i = t; i < cnt; i += 256) csr[base + i] = staged[i];
    } else {
        for (int i = t; i < cnt; i += 256) {
            Rec r = bcsr[base + i];
            int dl = r.meta >> 27;
            int p = atomicAdd(&dcur[dl], 1);
            csr[base + p] = r;
        }
    }
}

// xw = x @ W  -> packed-bf16 table (uint = 2 cols).  128 threads, 16 rows/block.
#define GR 16
__global__ void gemm_xw(const float* __restrict__ x, const float* __restrict__ W,
                        unsigned int* __restrict__ xwb, int N) {
    __shared__ float xs[GR][DD];
    int t = threadIdx.x;
    int r0 = blockIdx.x * GR;
    #pragma unroll
    for (int r = 0; r < GR; ++r) {
        int row = r0 + r;
        xs[r][t] = (row < N) ? x[row * DD + t] : 0.f;
    }
    __syncthreads();
    float acc[GR];
    #pragma unroll
    for (int r = 0; r < GR; ++r) acc[r] = 0.f;
    for (int k = 0; k < DD; k += 4) {
        float w0 = W[(k + 0) * DD + t];
        float w1 = W[(k + 1) * DD + t];
        float w2 = W[(k + 2) * DD + t];
        float w3 = W[(k + 3) * DD + t];
        #pragma unroll
        for (int r = 0; r < GR; ++r) {
            float4 xv = *(const float4*)&xs[r][k];
            acc[r] = fmaf(xv.x, w0, acc[r]);
            acc[r] = fmaf(xv.y, w1, acc[r]);
            acc[r] = fmaf(xv.z, w2, acc[r]);
            acc[r] = fmaf(xv.w, w3, acc[r]);
        }
    }
    #pragma unroll
    for (int r = 0; r < GR; ++r) {
        int row = r0 + r;
        float other = __shfl_xor(acc[r], 1);
        if (row < N && !(t & 1)) {
            unsigned int p = bf16rne(acc[r]) | (bf16rne(other) << 16);
            xwb[row * D2 + (t >> 1)] = p;
        }
    }
}

// Aggregation + LN + gelu.  4 waves/block, one node per wave (grid-stride).
// Within a wave: 4 groups of 16 lanes, each group takes every 4th edge;
// lane's chunk c = lane&15 covers cols 8c..8c+7 via one uint4 (16B) gather.
__global__ __launch_bounds__(256) void agg_ln_gelu(
    const uint4* __restrict__ xwb4, const Rec* __restrict__ csr,
    const int* __restrict__ row_ptr, const float* __restrict__ dinv,
    const float* __restrict__ bias, const float* __restrict__ gamma,
    const float* __restrict__ beta, float* __restrict__ out, int N)
{
    int wv = (blockIdx.x << 2) + (threadIdx.x >> 6);
    int lane = threadIdx.x & 63;
    int g = lane >> 4;
    int c = lane & 15;
    int nw = gridDim.x << 2;
    for (int i = wv; i < N; i += nw) {
        int beg = row_ptr[i], end = row_ptr[i + 1];
        float acc[8];
        #pragma unroll
        for (int k = 0; k < 8; ++k) acc[k] = 0.f;
        for (int j = beg + g; j < end; j += 4) {
            Rec er = csr[j];
            uint4 v = xwb4[(er.meta & 0x07FFFFFFu) * 16 + c];
            float w = er.w;
            acc[0] = fmaf(__uint_as_float(v.x << 16), w, acc[0]);
            acc[1] = fmaf(__uint_as_float(v.x & 0xFFFF0000u), w, acc[1]);
            acc[2] = fmaf(__uint_as_float(v.y << 16), w, acc[2]);
            acc[3] = fmaf(__uint_as_float(v.y & 0xFFFF0000u), w, acc[3]);
            acc[4] = fmaf(__uint_as_float(v.z << 16), w, acc[4]);
            acc[5] = fmaf(__uint_as_float(v.z & 0xFFFF0000u), w, acc[5]);
            acc[6] = fmaf(__uint_as_float(v.w << 16), w, acc[6]);
            acc[7] = fmaf(__uint_as_float(v.w & 0xFFFF0000u), w, acc[7]);
        }
        // merge the 4 edge-groups
        #pragma unroll
        for (int k = 0; k < 8; ++k) {
            acc[k] += __shfl_xor(acc[k], 16);
            acc[k] += __shfl_xor(acc[k], 32);
        }
        // self-loop + bias (all groups redundantly, identical values)
        float di = dinv[i];
        float sn = di * di;
        uint4 v = xwb4[i * 16 + c];
        acc[0] = fmaf(__uint_as_float(v.x << 16), sn, acc[0]);
        acc[1] = fmaf(__uint_as_float(v.x & 0xFFFF0000u), sn, acc[1]);
        acc[2] = fmaf(__uint_as_float(v.y << 16), sn, acc[2]);
        acc[3] = fmaf(__uint_as_float(v.y & 0xFFFF0000u), sn, acc[3]);
        acc[4] = fmaf(__uint_as_float(v.z << 16), sn, acc[4]);
        acc[5] = fmaf(__uint_as_float(v.z & 0xFFFF0000u), sn, acc[5]);
        acc[6] = fmaf(__uint_as_float(v.w << 16), sn, acc[6]);
        acc[7] = fmaf(__uint_as_float(v.w & 0xFFFF0000u), sn, acc[7]);
        float4 b0 = ((const float4*)bias)[c * 2];
        float4 b1 = ((const float4*)bias)[c * 2 + 1];
        acc[0] += b0.x; acc[1] += b0.y; acc[2] += b0.z; acc[3] += b0.w;
        acc[4] += b1.x; acc[5] += b1.y; acc[6] += b1.z; acc[7] += b1.w;
        // LayerNorm over 128 (chunks are lanes 0..15 within each group)
        float sum = 0.f, sq = 0.f;
        #pragma unroll
        for (int k = 0; k < 8; ++k) { sum += acc[k]; sq += acc[k] * acc[k]; }
        #pragma unroll
        for (int o = 1; o < 16; o <<= 1) {
            sum += __shfl_xor(sum, o);
            sq  += __shfl_xor(sq, o);
        }
        float mu   = sum * (1.f / DD);
        float var  = sq * (1.f / DD) - mu * mu;
        float rstd = rsqrtf(var + 1e-5f);
        float4 g0 = ((const float4*)gamma)[c * 2];
        float4 g1 = ((const float4*)gamma)[c * 2 + 1];
        float4 e0 = ((const float4*)beta)[c * 2];
        float4 e1 = ((const float4*)beta)[c * 2 + 1];
        float gg[8] = { g0.x, g0.y, g0.z, g0.w, g1.x, g1.y, g1.z, g1.w };
        float ee[8] = { e0.x, e0.y, e0.z, e0.w, e1.x, e1.y, e1.z, e1.w };
        float y[8];
        #pragma unroll
        for (int k = 0; k < 8; ++k) {
            float t0 = (acc[k] - mu) * rstd * gg[k] + ee[k];
            y[k] = 0.5f * t0 * (1.f + tanhf(0.7978845608f * (t0 + 0.044715f * t0 * t0 * t0)));
        }
        if (g == 0) {
            float4 o0 = { y[0], y[1], y[2], y[3] };
            float4 o1 = { y[4], y[5], y[6], y[7] };
            ((float4*)out)[i * 32 + c * 2]     = o0;
            ((float4*)out)[i * 32 + c * 2 + 1] = o1;
        }
    }
}

static inline size_t align_up(size_t x, size_t a) { return (x + a - 1) & ~(a - 1); }

extern "C" void kernel_launch(void* const* d_in, const int* in_sizes, int n_in,
                              void* d_out, int out_size, void* d_ws, size_t ws_size,
                              hipStream_t stream) {
    const float* z      = (const float*)d_in[0];
    const int*   ei     = (const int*)d_in[1];
    const float* Ws     = (const float*)d_in[2];
    const float* bs     = (const float*)d_in[3];
    const float* gammas = (const float*)d_in[4];
    const float* betas  = (const float*)d_in[5];

    int E  = in_sizes[1] / 2;
    int LD = in_sizes[3];
    int Dd = in_sizes[2] / LD;            // 128
    int L  = LD / Dd;
    int N  = in_sizes[0] / Dd;
    int NB = (N + BW_DST - 1) / BW_DST;   // 313

    const int* srcp = ei;
    const int* dstp = ei + E;

    char* ws = (char*)d_ws;
    size_t off = 0;
    int* degi = (int*)(ws + off);        off = align_up(off + (size_t)N * 4, 256);
    float* dinv = (float*)(ws + off);    off = align_up(off + (size_t)N * 4, 256);
    int* row_ptr = (int*)(ws + off);     off = align_up(off + (size_t)(N + 1) * 4, 256);
    int* bcur = (int*)(ws + off);        off = align_up(off + (size_t)NB * 4, 256);
    Rec* bcsr = (Rec*)(ws + off);        off = align_up(off + (size_t)E * 8, 256);
    Rec* csr = (Rec*)(ws + off);         off = align_up(off + (size_t)E * 8, 256);
    unsigned int* xwb = (unsigned int*)(ws + off); off = align_up(off + (size_t)N * D2 * 4, 256);
    float* xb = (float*)(ws + off);      off = align_up(off + (size_t)N * Dd * 4, 256);
    float* dout = (float*)d_out;
    (void)ws_size; (void)n_in; (void)out_size;

    int nb_n = (N + 255) / 256;
    int nb_e = (E + 255) / 256;
    int nb_p1 = (E + BATCH - 1) / BATCH;
    int nb_agg = (N + 3) / 4;

    init_deg<<<nb_n, 256, 0, stream>>>(degi, N);
    hist_dst<<<nb_e, 256, 0, stream>>>(dstp, E, degi);
    scan_all<<<1, 256, 0, stream>>>(degi, dinv, row_ptr, bcur, N, E);
    bucket_fill<<<nb_p1, 256, 0, stream>>>(srcp, dstp, E, dinv, bcur, bcsr, NB);
    fine_sort<<<NB, 256, 0, stream>>>(row_ptr, bcsr, csr, N);

    const float* cur = z;
    for (int li = 0; li < L; ++li) {
        gemm_xw<<<(N + GR - 1) / GR, DD, 0, stream>>>(cur, Ws + (size_t)li * Dd * Dd, xwb, N);
        float* outp = (li == L - 1) ? dout : xb;
        agg_ln_gelu<<<nb_agg, 256, 0, stream>>>((const uint4*)xwb, csr, row_ptr, dinv,
                                                bs + (size_t)li * Dd, gammas + (size_t)li * Dd,
                                                betas + (size_t)li * Dd, outp, N);
        cur = outp;
    }
}

// Round 7
// 224.581 us; speedup vs baseline: 4.8736x; 1.1574x over previous
//
#include <hip/hip_runtime.h>

#define DD 128
#define D2 64        // DD/2 packed-uint columns
#define BW_DST 32
#define BW_SHIFT 5
#define BATCH 4096
#define NBPAD 320    // >= ceil(N/32) = 313
#define P2CAP 2880

struct alignas(8) Rec { unsigned int meta; float w; };  // meta = src | (dstloc<<27)

__device__ __forceinline__ unsigned int bf16rne(float f) {
    unsigned int u = __float_as_uint(f);
    unsigned int r = ((u >> 16) & 1u) + 0x7fffu;   // round-to-nearest-even
    return (u + r) >> 16;
}
__device__ __forceinline__ float bflo(unsigned int v) { return __uint_as_float(v << 16); }
__device__ __forceinline__ float bfhi(unsigned int v) { return __uint_as_float(v & 0xFFFF0000u); }

__global__ void init_deg(int* __restrict__ degi, int N) {
    int i = blockIdx.x * blockDim.x + threadIdx.x;
    if (i < N) degi[i] = 1;   // self-loop
}

__global__ void hist_dst(const int* __restrict__ dst, int E, int* __restrict__ degi) {
    int e = blockIdx.x * blockDim.x + threadIdx.x;
    if (e < E) atomicAdd(&degi[dst[e]], 1);
}

// Single block: dinv + exclusive scan of edge counts -> row_ptr + bucket cursors.
__global__ void scan_all(const int* __restrict__ degi, float* __restrict__ dinv,
                         int* __restrict__ row_ptr, int* __restrict__ bcur,
                         int N, int E) {
    __shared__ int part[256];
    int t = threadIdx.x;
    for (int i = t; i < N; i += 256) dinv[i] = rsqrtf((float)degi[i]);
    int chunk = (N + 255) / 256;
    int lo = t * chunk, hi = min(lo + chunk, N);
    int s = 0;
    for (int i = lo; i < hi; ++i) s += degi[i] - 1;
    part[t] = s;
    __syncthreads();
    for (int o = 1; o < 256; o <<= 1) {
        int v = (t >= o) ? part[t - o] : 0;
        __syncthreads();
        part[t] += v;
        __syncthreads();
    }
    int run = (t == 0) ? 0 : part[t - 1];
    for (int i = lo; i < hi; ++i) {
        row_ptr[i] = run;
        if ((i & (BW_DST - 1)) == 0) bcur[i >> BW_SHIFT] = run;
        run += degi[i] - 1;
    }
    if (t == 0) row_ptr[N] = E;
}

// Pass 1: LDS counting-sort per 4096-edge batch, contiguous per-bucket flush.
__global__ __launch_bounds__(256) void bucket_fill(
    const int* __restrict__ src, const int* __restrict__ dst, int E,
    const float* __restrict__ dinv, int* __restrict__ bcur,
    Rec* __restrict__ bcsr, int NB)
{
    __shared__ unsigned short sbkt[BATCH];
    __shared__ int cnt[NBPAD];
    __shared__ int boff[NBPAD + 1];
    __shared__ int gbase[NBPAD];
    __shared__ int lcur[NBPAD];
    __shared__ Rec staged[BATCH];
    __shared__ int wpart[256];
    int t = threadIdx.x;

    for (int base = blockIdx.x * BATCH; base < E; base += gridDim.x * BATCH) {
        int n = min(E - base, BATCH);
        for (int b = t; b < NB; b += 256) cnt[b] = 0;
        __syncthreads();
        for (int i = t; i < n; i += 256) {
            int d = dst[base + i];
            int bk = d >> BW_SHIFT;
            sbkt[i] = (unsigned short)bk;
            atomicAdd(&cnt[bk], 1);
        }
        __syncthreads();
        int chunk = (NB + 255) / 256;
        int lo = t * chunk, hi = min(lo + chunk, NB);
        int s = 0;
        for (int b = lo; b < hi; ++b) s += cnt[b];
        wpart[t] = s;
        __syncthreads();
        for (int o = 1; o < 256; o <<= 1) {
            int v = (t >= o) ? wpart[t - o] : 0;
            __syncthreads();
            wpart[t] += v;
            __syncthreads();
        }
        int run = (t == 0) ? 0 : wpart[t - 1];
        for (int b = lo; b < hi; ++b) {
            boff[b] = run;
            lcur[b] = run;
            if (cnt[b] > 0) gbase[b] = atomicAdd(&bcur[b], cnt[b]);
            run += cnt[b];
        }
        if (t == 0) boff[NB] = n;
        __syncthreads();
        for (int i = t; i < n; i += 256) {
            int e = base + i;
            int ss = src[e], dd = dst[e];
            int bk = sbkt[i];
            int p = atomicAdd(&lcur[bk], 1);
            Rec r;
            r.meta = (unsigned int)ss | ((unsigned int)(dd & (BW_DST - 1)) << 27);
            r.w = dinv[ss] * dinv[dd];
            staged[p] = r;
        }
        __syncthreads();
        int wid = t >> 6, lane = t & 63;
        for (int b = wid; b < NB; b += 4) {
            int s0 = boff[b];
            int c = boff[b + 1] - s0;
            if (c == 0) continue;
            int g = gbase[b];
            for (int j = lane; j < c; j += 64) bcsr[g + j] = staged[s0 + j];
        }
        __syncthreads();
    }
}

// Pass 2: per bucket, fine-sort by dst via LDS, write coalesced.
__global__ __launch_bounds__(256) void fine_sort(
    const int* __restrict__ row_ptr, const Rec* __restrict__ bcsr,
    Rec* __restrict__ csr, int N)
{
    __shared__ Rec staged[P2CAP];
    __shared__ int dcur[BW_DST];
    int b = blockIdx.x;
    int d0 = b * BW_DST;
    int nd = min(BW_DST, N - d0);
    int base = row_ptr[d0];
    int end  = row_ptr[min(d0 + nd, N)];
    int cnt  = end - base;
    int t = threadIdx.x;
    if (t < nd) dcur[t] = row_ptr[d0 + t] - base;
    __syncthreads();
    if (cnt <= P2CAP) {
        for (int i = t; i < cnt; i += 256) {
            Rec r = bcsr[base + i];
            int dl = r.meta >> 27;
            int p = atomicAdd(&dcur[dl], 1);
            staged[p] = r;
        }
        __syncthreads();
        for (int i = t; i < cnt; i += 256) csr[base + i] = staged[i];
    } else {
        for (int i = t; i < cnt; i += 256) {
            Rec r = bcsr[base + i];
            int dl = r.meta >> 27;
            int p = atomicAdd(&dcur[dl], 1);
            csr[base + p] = r;
        }
    }
}

// xw = x @ W  -> packed-bf16 table (uint = 2 cols).  128 threads, 16 rows/block.
#define GR 16
__global__ void gemm_xw(const float* __restrict__ x, const float* __restrict__ W,
                        unsigned int* __restrict__ xwb, int N) {
    __shared__ float xs[GR][DD];
    int t = threadIdx.x;
    int r0 = blockIdx.x * GR;
    #pragma unroll
    for (int r = 0; r < GR; ++r) {
        int row = r0 + r;
        xs[r][t] = (row < N) ? x[row * DD + t] : 0.f;
    }
    __syncthreads();
    float acc[GR];
    #pragma unroll
    for (int r = 0; r < GR; ++r) acc[r] = 0.f;
    for (int k = 0; k < DD; k += 4) {
        float w0 = W[(k + 0) * DD + t];
        float w1 = W[(k + 1) * DD + t];
        float w2 = W[(k + 2) * DD + t];
        float w3 = W[(k + 3) * DD + t];
        #pragma unroll
        for (int r = 0; r < GR; ++r) {
            float4 xv = *(const float4*)&xs[r][k];
            acc[r] = fmaf(xv.x, w0, acc[r]);
            acc[r] = fmaf(xv.y, w1, acc[r]);
            acc[r] = fmaf(xv.z, w2, acc[r]);
            acc[r] = fmaf(xv.w, w3, acc[r]);
        }
    }
    #pragma unroll
    for (int r = 0; r < GR; ++r) {
        int row = r0 + r;
        float other = __shfl_xor(acc[r], 1);
        if (row < N && !(t & 1)) {
            unsigned int p = bf16rne(acc[r]) | (bf16rne(other) << 16);
            xwb[row * D2 + (t >> 1)] = p;
        }
    }
}

// Fused: aggregate(layer li) + LN + gelu  ->  GEMM with W(layer li+1) -> bf16 table.
// 512 threads = 8 waves = 8 nodes (one per wave, R3-proven agg structure), then
// an 8-row GEMM from LDS.
__global__ __launch_bounds__(512) void agg_gemm(
    const unsigned int* __restrict__ xwb_in, const Rec* __restrict__ csr,
    const int* __restrict__ row_ptr, const float* __restrict__ dinv,
    const float* __restrict__ bias, const float* __restrict__ gamma,
    const float* __restrict__ beta, const float* __restrict__ W,
    unsigned int* __restrict__ xwb_out, int N)
{
    __shared__ float xs[8][DD];
    int t = threadIdx.x;
    int wid = t >> 6, l = t & 63;
    int i = blockIdx.x * 8 + wid;
    // Phase A: aggregate + LN + gelu -> LDS row (identical math to proven agg)
    if (i < N) {
        int beg = row_ptr[i], end = row_ptr[i + 1];
        float ax = 0.f, ay = 0.f;
        #pragma unroll 4
        for (int j = beg; j < end; ++j) {
            Rec er = csr[j];                    // wave-uniform -> scalar load
            unsigned int v = xwb_in[(er.meta & 0x07FFFFFFu) * D2 + l];
            ax = fmaf(bflo(v), er.w, ax);
            ay = fmaf(bfhi(v), er.w, ay);
        }
        float di = dinv[i], sn = di * di;
        unsigned int v = xwb_in[i * D2 + l];
        ax = fmaf(bflo(v), sn, ax);
        ay = fmaf(bfhi(v), sn, ay);
        float2 b2 = ((const float2*)bias)[l];
        ax += b2.x; ay += b2.y;
        float sum = ax + ay, sq = ax * ax + ay * ay;
        #pragma unroll
        for (int o = 32; o > 0; o >>= 1) { sum += __shfl_xor(sum, o); sq += __shfl_xor(sq, o); }
        float mu   = sum * (1.f / DD);
        float var  = sq * (1.f / DD) - mu * mu;
        float rstd = rsqrtf(var + 1e-5f);
        float2 g2  = ((const float2*)gamma)[l];
        float2 be2 = ((const float2*)beta)[l];
        float y0 = (ax - mu) * rstd * g2.x + be2.x;
        float y1 = (ay - mu) * rstd * g2.y + be2.y;
        y0 = 0.5f * y0 * (1.f + tanhf(0.7978845608f * (y0 + 0.044715f * y0 * y0 * y0)));
        y1 = 0.5f * y1 * (1.f + tanhf(0.7978845608f * (y1 + 0.044715f * y1 * y1 * y1)));
        xs[wid][2 * l]     = y0;
        xs[wid][2 * l + 1] = y1;
    } else {
        xs[wid][2 * l]     = 0.f;
        xs[wid][2 * l + 1] = 0.f;
    }
    __syncthreads();
    // Phase B: 8-row GEMM vs W, pack bf16 pairs
    int col = t & 127, h = t >> 7;   // h in 0..3 -> rows 2h, 2h+1
    float a0 = 0.f, a1 = 0.f;
    for (int k = 0; k < DD; k += 4) {
        float w0 = W[(k + 0) * DD + col];
        float w1 = W[(k + 1) * DD + col];
        float w2 = W[(k + 2) * DD + col];
        float w3 = W[(k + 3) * DD + col];
        float4 x0 = *(const float4*)&xs[h * 2 + 0][k];
        float4 x1 = *(const float4*)&xs[h * 2 + 1][k];
        a0 = fmaf(x0.x, w0, a0); a0 = fmaf(x0.y, w1, a0);
        a0 = fmaf(x0.z, w2, a0); a0 = fmaf(x0.w, w3, a0);
        a1 = fmaf(x1.x, w0, a1); a1 = fmaf(x1.y, w1, a1);
        a1 = fmaf(x1.z, w2, a1); a1 = fmaf(x1.w, w3, a1);
    }
    int row0 = blockIdx.x * 8 + h * 2;
    float o0 = __shfl_xor(a0, 1);
    float o1 = __shfl_xor(a1, 1);
    if (!(t & 1)) {
        if (row0 < N)
            xwb_out[row0 * D2 + (col >> 1)] = bf16rne(a0) | (bf16rne(o0) << 16);
        if (row0 + 1 < N)
            xwb_out[(row0 + 1) * D2 + (col >> 1)] = bf16rne(a1) | (bf16rne(o1) << 16);
    }
}

// Final layer: aggregate + LN + gelu -> f32 output.  One wave per node (R3-proven).
__global__ void agg_ln_gelu(const unsigned int* __restrict__ xwb, const Rec* __restrict__ csr,
                            const int* __restrict__ row_ptr, const float* __restrict__ dinv,
                            const float* __restrict__ bias, const float* __restrict__ gamma,
                            const float* __restrict__ beta, float* __restrict__ out) {
    int i = blockIdx.x;
    int l = threadIdx.x;
    int beg = row_ptr[i], end = row_ptr[i + 1];
    float ax = 0.f, ay = 0.f;
    #pragma unroll 4
    for (int j = beg; j < end; ++j) {
        Rec er = csr[j];
        unsigned int v = xwb[(er.meta & 0x07FFFFFFu) * D2 + l];
        ax = fmaf(bflo(v), er.w, ax);
        ay = fmaf(bfhi(v), er.w, ay);
    }
    float di = dinv[i], sn = di * di;
    unsigned int v = xwb[i * D2 + l];
    ax = fmaf(bflo(v), sn, ax);
    ay = fmaf(bfhi(v), sn, ay);
    float2 b2 = ((const float2*)bias)[l];
    ax += b2.x; ay += b2.y;
    float sum = ax + ay, sq = ax * ax + ay * ay;
    #pragma unroll
    for (int o = 32; o > 0; o >>= 1) { sum += __shfl_xor(sum, o); sq += __shfl_xor(sq, o); }
    float mu   = sum * (1.f / DD);
    float var  = sq * (1.f / DD) - mu * mu;
    float rstd = rsqrtf(var + 1e-5f);
    float2 g2  = ((const float2*)gamma)[l];
    float2 be2 = ((const float2*)beta)[l];
    float y0 = (ax - mu) * rstd * g2.x + be2.x;
    float y1 = (ay - mu) * rstd * g2.y + be2.y;
    y0 = 0.5f * y0 * (1.f + tanhf(0.7978845608f * (y0 + 0.044715f * y0 * y0 * y0)));
    y1 = 0.5f * y1 * (1.f + tanhf(0.7978845608f * (y1 + 0.044715f * y1 * y1 * y1)));
    float2 o2; o2.x = y0; o2.y = y1;
    ((float2*)out)[i * D2 + l] = o2;
}

static inline size_t align_up(size_t x, size_t a) { return (x + a - 1) & ~(a - 1); }

extern "C" void kernel_launch(void* const* d_in, const int* in_sizes, int n_in,
                              void* d_out, int out_size, void* d_ws, size_t ws_size,
                              hipStream_t stream) {
    const float* z      = (const float*)d_in[0];
    const int*   ei     = (const int*)d_in[1];
    const float* Ws     = (const float*)d_in[2];
    const float* bs     = (const float*)d_in[3];
    const float* gammas = (const float*)d_in[4];
    const float* betas  = (const float*)d_in[5];

    int E  = in_sizes[1] / 2;
    int LD = in_sizes[3];
    int Dd = in_sizes[2] / LD;            // 128
    int L  = LD / Dd;
    int N  = in_sizes[0] / Dd;
    int NB = (N + BW_DST - 1) / BW_DST;   // 313

    const int* srcp = ei;
    const int* dstp = ei + E;

    char* ws = (char*)d_ws;
    size_t off = 0;
    int* degi = (int*)(ws + off);        off = align_up(off + (size_t)N * 4, 256);
    float* dinv = (float*)(ws + off);    off = align_up(off + (size_t)N * 4, 256);
    int* row_ptr = (int*)(ws + off);     off = align_up(off + (size_t)(N + 1) * 4, 256);
    int* bcur = (int*)(ws + off);        off = align_up(off + (size_t)NB * 4, 256);
    Rec* bcsr = (Rec*)(ws + off);        off = align_up(off + (size_t)E * 8, 256);
    Rec* csr = (Rec*)(ws + off);         off = align_up(off + (size_t)E * 8, 256);
    unsigned int* xwb_a = (unsigned int*)(ws + off); off = align_up(off + (size_t)N * D2 * 4, 256);
    unsigned int* xwb_b = (unsigned int*)(ws + off); off = align_up(off + (size_t)N * D2 * 4, 256);
    float* dout = (float*)d_out;
    (void)ws_size; (void)n_in; (void)out_size;

    int nb_n = (N + 255) / 256;
    int nb_e = (E + 255) / 256;
    int nb_p1 = (E + BATCH - 1) / BATCH;

    init_deg<<<nb_n, 256, 0, stream>>>(degi, N);
    hist_dst<<<nb_e, 256, 0, stream>>>(dstp, E, degi);
    scan_all<<<1, 256, 0, stream>>>(degi, dinv, row_ptr, bcur, N, E);
    bucket_fill<<<nb_p1, 256, 0, stream>>>(srcp, dstp, E, dinv, bcur, bcsr, NB);
    fine_sort<<<NB, 256, 0, stream>>>(row_ptr, bcsr, csr, N);

    // layer 0 dense transform from z
    gemm_xw<<<(N + GR - 1) / GR, DD, 0, stream>>>(z, Ws, xwb_a, N);

    // middle layers: fused agg(li)+LN+gelu -> GEMM W(li+1)
    unsigned int* tin = xwb_a;
    unsigned int* tout = xwb_b;
    for (int li = 0; li < L - 1; ++li) {
        agg_gemm<<<(N + 7) / 8, 512, 0, stream>>>(
            tin, csr, row_ptr, dinv,
            bs + (size_t)li * Dd, gammas + (size_t)li * Dd, betas + (size_t)li * Dd,
            Ws + (size_t)(li + 1) * Dd * Dd, tout, N);
        unsigned int* tmp = tin; tin = tout; tout = tmp;
    }

    // final layer: agg + LN + gelu -> f32 out
    agg_ln_gelu<<<N, 64, 0, stream>>>(tin, csr, row_ptr, dinv,
                                      bs + (size_t)(L - 1) * Dd,
                                      gammas + (size_t)(L - 1) * Dd,
                                      betas + (size_t)(L - 1) * Dd, dout);
}